// Round 5
// baseline (20.792 us; speedup 1.0000x reference)
//
#include <hip/hip_runtime.h>
#include <math.h>

#define L 512
#define TILE_T 32
#define NTHREADS 256
#define NACT_MAX 136      // bound: active rows have distinct integer C_{l-1} in a 132.5-wide interval -> <=134
#define ZWIN 14.5f        // fp32 exp (incl. denormals) underflows at |z| ~ 14.42

static constexpr float EPS = 1e-6f;
static constexpr float INV_SQRT_2PI = 0.39894228040143267794f;

__global__ __launch_bounds__(NTHREADS, 6) void ge_kernel(
    const float* __restrict__ text,  // [B, L, D]
    const int*   __restrict__ durs,  // [B, L]
    float*       __restrict__ out,   // [B, T, D]
    int B, int D, int T, int tilesPerB)
{
    __shared__ float s_lmean[NACT_MAX];
    __shared__ float s_lisig[NACT_MAX];
    __shared__ int   s_lrow[NACT_MAX];
    __shared__ float s_probs[NACT_MAX][TILE_T];
    __shared__ float s_wtot[4];
    __shared__ int   s_wcnt[4];
    __shared__ float s_wsum[4][TILE_T];
    __shared__ float s_norm[TILE_T];

    const int tid  = threadIdx.x;
    const int lane = tid & 63;
    const int wid  = tid >> 6;
    const int blk  = blockIdx.x;
    const int b    = blk / tilesPerB;
    const int t0   = (blk % tilesPerB) * TILE_T;

    // ---- stage 0: durs -> cumsum (wave scan) -> mean, 1/sigma; build active-row list ----
    const int l0 = 2 * tid;
    const float d0 = (float)durs[b * L + l0];
    const float d1 = (float)durs[b * L + l0 + 1];
    const float pairsum = d0 + d1;

    float v = pairsum;
    #pragma unroll
    for (int off = 1; off < 64; off <<= 1) {
        float n = __shfl_up(v, off, 64);
        if (lane >= off) v += n;
    }
    if (lane == 63) s_wtot[wid] = v;
    __syncthreads();
    float wpre = 0.f;
    for (int w = 0; w < wid; ++w) wpre += s_wtot[w];
    const float excl = wpre + v - pairsum;    // cumsum before row l0

    const float cum0  = excl + d0;
    const float cum1  = cum0 + d1;
    const float mean0 = cum0 + 0.5f * d0;
    const float mean1 = cum1 + 0.5f * d1;
    const float sig0  = 0.5f * d0 + EPS;
    const float sig1  = 0.5f * d1 + EPS;
    const float isig0 = 1.0f / sig0;
    const float isig1 = 1.0f / sig1;

    const float tlo = (float)t0 + 0.5f;
    const float thi = (float)t0 + (float)TILE_T - 0.5f;
    const float r0 = ZWIN * sig0;
    const float r1 = ZWIN * sig1;
    const bool act0 = (d0 >= 1.f) && (mean0 + r0 >= tlo) && (mean0 - r0 <= thi);
    const bool act1 = (d1 >= 1.f) && (mean1 + r1 >= tlo) && (mean1 - r1 <= thi);

    const unsigned long long m0 = __ballot(act0);
    const unsigned long long m1 = __ballot(act1);
    const unsigned long long lt = (lane == 0) ? 0ull : ((~0ull) >> (64 - lane));
    const int off_in_wave = __popcll(m0 & lt) + __popcll(m1 & lt);
    const int cnt_wave = __popcll(m0) + __popcll(m1);
    if (lane == 0) s_wcnt[wid] = cnt_wave;
    __syncthreads();
    int base_w = 0;
    for (int w = 0; w < wid; ++w) base_w += s_wcnt[w];
    const int nact = s_wcnt[0] + s_wcnt[1] + s_wcnt[2] + s_wcnt[3];

    if (act0) {
        const int i = base_w + off_in_wave;
        s_lrow[i] = l0; s_lmean[i] = mean0; s_lisig[i] = isig0;
    }
    if (act1) {
        const int i = base_w + off_in_wave + (act0 ? 1 : 0);
        s_lrow[i] = l0 + 1; s_lmean[i] = mean1; s_lisig[i] = isig1;
    }
    __syncthreads();

    // ---- stage 1: probs for listed rows; per-t norm sums ----
    float psum = 0.f;                         // partial for tt = tid & 31
    const int   mytt = tid & 31;
    const float myt  = (float)(t0 + mytt) + 0.5f;
    const int total = nact * TILE_T;
    for (int idx = tid; idx < total; idx += NTHREADS) {
        const int i = idx >> 5;               // (idx & 31) == mytt
        const float isg = s_lisig[i];
        const float z = (myt - s_lmean[i]) * isg;
        const float p = __expf(-0.5f * z * z) * isg * INV_SQRT_2PI;
        s_probs[i][mytt] = p;
        psum += p;
    }
    psum += __shfl_xor(psum, 32, 64);
    if (lane < 32) s_wsum[wid][lane] = psum;
    __syncthreads();
    if (tid < TILE_T) {
        const float s = s_wsum[0][tid] + s_wsum[1][tid] + s_wsum[2][tid] + s_wsum[3][tid];
        s_norm[tid] = 1.0f / (s + EPS);
    }
    __syncthreads();

    // ---- stage 2: wave wid owns tt = 8*wid..8*wid+7; thread owns d-quad lane*4 ----
    float4 a[8];
    #pragma unroll
    for (int k = 0; k < 8; ++k) a[k] = make_float4(0.f, 0.f, 0.f, 0.f);

    const float* tbase = text + (size_t)b * L * D + (lane << 2);
    const float* sprow = &s_probs[0][wid << 3];
    if (nact > 0) {
        float4 vnext = *(const float4*)(tbase + (size_t)s_lrow[0] * D);
        for (int i = 0; i < nact; ++i) {
            const float4 val = vnext;
            if (i + 1 < nact)
                vnext = *(const float4*)(tbase + (size_t)s_lrow[i + 1] * D);
            const float4 p0 = *(const float4*)(sprow + i * TILE_T + 0);  // wave-uniform broadcast
            const float4 p1 = *(const float4*)(sprow + i * TILE_T + 4);
            const float pw[8] = {p0.x, p0.y, p0.z, p0.w, p1.x, p1.y, p1.z, p1.w};
            #pragma unroll
            for (int k = 0; k < 8; ++k) {
                a[k].x += pw[k] * val.x;
                a[k].y += pw[k] * val.y;
                a[k].z += pw[k] * val.z;
                a[k].w += pw[k] * val.w;
            }
        }
    }

    // ---- stage 3: normalize + store (wave stores 8 consecutive t rows) ----
    const int tt0 = t0 + (wid << 3);
    float* obase = out + ((size_t)b * T + tt0) * D + (lane << 2);
    #pragma unroll
    for (int j = 0; j < 8; ++j) {
        if (tt0 + j < T) {
            const float n = s_norm[(wid << 3) + j];
            const float4 o = make_float4(a[j].x * n, a[j].y * n, a[j].z * n, a[j].w * n);
            *(float4*)(obase + (size_t)j * D) = o;
        }
    }
}

extern "C" void kernel_launch(void* const* d_in, const int* in_sizes, int n_in,
                              void* d_out, int out_size, void* d_ws, size_t ws_size,
                              hipStream_t stream) {
    const float* text = (const float*)d_in[0];
    const int*   durs = (const int*)d_in[1];
    float*       out  = (float*)d_out;

    const int BL = in_sizes[1];        // B * L
    const int D  = in_sizes[0] / BL;   // 256
    const int B  = BL / L;             // 16
    const int T  = out_size / (B * D); // 2048
    const int tilesPerB = (T + TILE_T - 1) / TILE_T;

    ge_kernel<<<dim3(B * tilesPerB), dim3(NTHREADS), 0, stream>>>(
        text, durs, out, B, D, T, tilesPerB);
}

// Round 6
// 18.089 us; speedup vs baseline: 1.1495x; 1.1495x over previous
//
#include <hip/hip_runtime.h>
#include <math.h>

#define L 512
#define TILE_T 16
#define NTHREADS 256
#define NACT_MAX 160      // bound: active rows have distinct integer C_{l-1} in a ~117-wide interval
#define ZWIN 14.5f        // fp32 exp (incl. denormals) underflows at |z| ~ 14.42
#define NXCD 8

static constexpr float EPS = 1e-6f;
static constexpr float INV_SQRT_2PI = 0.39894228040143267794f;

__global__ __launch_bounds__(NTHREADS, 8) void ge_kernel(
    const float* __restrict__ text,  // [B, L, D]
    const int*   __restrict__ durs,  // [B, L]
    float*       __restrict__ out,   // [B, T, D]
    int B, int D, int T, int tilesPerB, int nwg)
{
    __shared__ float s_lmean[NACT_MAX];
    __shared__ float s_lisig[NACT_MAX];
    __shared__ int   s_lrow[NACT_MAX];
    __shared__ float s_probs[NACT_MAX][TILE_T];
    __shared__ float s_wtot[4];
    __shared__ int   s_wcnt[4];
    __shared__ float s_wsum[4][TILE_T];
    __shared__ float s_norm[TILE_T];

    const int tid  = threadIdx.x;
    const int lane = tid & 63;
    const int wid  = tid >> 6;

    // XCD-aware bijective swizzle (nwg % NXCD == 0): XCD k owns contiguous wg chunk
    const int orig = blockIdx.x;
    const int wg   = (orig & (NXCD - 1)) * (nwg / NXCD) + (orig >> 3);
    const int b    = wg / tilesPerB;
    const int t0   = (wg % tilesPerB) * TILE_T;

    // ---- stage 0: durs -> cumsum (wave scan) -> mean, 1/sigma; build active-row list ----
    const int l0 = 2 * tid;
    const float d0 = (float)durs[b * L + l0];
    const float d1 = (float)durs[b * L + l0 + 1];
    const float pairsum = d0 + d1;

    float v = pairsum;
    #pragma unroll
    for (int off = 1; off < 64; off <<= 1) {
        float n = __shfl_up(v, off, 64);
        if (lane >= off) v += n;
    }
    if (lane == 63) s_wtot[wid] = v;
    __syncthreads();
    float wpre = 0.f;
    for (int w = 0; w < wid; ++w) wpre += s_wtot[w];
    const float excl = wpre + v - pairsum;    // cumsum before row l0

    const float cum0  = excl + d0;
    const float cum1  = cum0 + d1;
    const float mean0 = cum0 + 0.5f * d0;
    const float mean1 = cum1 + 0.5f * d1;
    const float sig0  = 0.5f * d0 + EPS;
    const float sig1  = 0.5f * d1 + EPS;
    const float isig0 = 1.0f / sig0;
    const float isig1 = 1.0f / sig1;

    const float tlo = (float)t0 + 0.5f;
    const float thi = (float)t0 + (float)TILE_T - 0.5f;
    const float r0 = ZWIN * sig0;
    const float r1 = ZWIN * sig1;
    const bool act0 = (d0 >= 1.f) && (mean0 + r0 >= tlo) && (mean0 - r0 <= thi);
    const bool act1 = (d1 >= 1.f) && (mean1 + r1 >= tlo) && (mean1 - r1 <= thi);

    const unsigned long long m0 = __ballot(act0);
    const unsigned long long m1 = __ballot(act1);
    const unsigned long long lt = (lane == 0) ? 0ull : ((~0ull) >> (64 - lane));
    const int off_in_wave = __popcll(m0 & lt) + __popcll(m1 & lt);
    const int cnt_wave = __popcll(m0) + __popcll(m1);
    if (lane == 0) s_wcnt[wid] = cnt_wave;
    __syncthreads();
    int base_w = 0;
    for (int w = 0; w < wid; ++w) base_w += s_wcnt[w];
    const int nact = s_wcnt[0] + s_wcnt[1] + s_wcnt[2] + s_wcnt[3];

    if (act0) {
        const int i = base_w + off_in_wave;
        s_lrow[i] = l0; s_lmean[i] = mean0; s_lisig[i] = isig0;
    }
    if (act1) {
        const int i = base_w + off_in_wave + (act0 ? 1 : 0);
        s_lrow[i] = l0 + 1; s_lmean[i] = mean1; s_lisig[i] = isig1;
    }
    __syncthreads();

    // ---- stage 1: probs for listed rows; per-t norm sums ----
    float psum = 0.f;                         // partial for tt = tid & 15
    const int   mytt = tid & 15;
    const float myt  = (float)(t0 + mytt) + 0.5f;
    const int total = nact * TILE_T;
    for (int idx = tid; idx < total; idx += NTHREADS) {
        const int i = idx >> 4;               // (idx & 15) == mytt
        const float isg = s_lisig[i];
        const float z = (myt - s_lmean[i]) * isg;
        const float p = __expf(-0.5f * z * z) * isg * INV_SQRT_2PI;
        s_probs[i][mytt] = p;
        psum += p;
    }
    psum += __shfl_xor(psum, 16, 64);
    psum += __shfl_xor(psum, 32, 64);
    if (lane < 16) s_wsum[wid][lane] = psum;
    __syncthreads();
    if (tid < TILE_T) {
        const float s = s_wsum[0][tid] + s_wsum[1][tid] + s_wsum[2][tid] + s_wsum[3][tid];
        s_norm[tid] = 1.0f / (s + EPS);
    }
    __syncthreads();

    // ---- stage 2: wave wid owns tt = 4*wid..4*wid+3; thread owns d-quad lane*4 ----
    float4 a0 = {0,0,0,0}, a1 = {0,0,0,0}, a2 = {0,0,0,0}, a3 = {0,0,0,0};
    const float* tbase = text + (size_t)b * L * D + (lane << 2);
    if (nact > 0) {
        float4 vnext = *(const float4*)(tbase + (size_t)s_lrow[0] * D);
        for (int i = 0; i < nact; ++i) {
            const float4 val = vnext;
            if (i + 1 < nact)
                vnext = *(const float4*)(tbase + (size_t)s_lrow[i + 1] * D);
            const float4 p = *(const float4*)&s_probs[i][wid << 2];  // wave-uniform broadcast
            a0.x += p.x * val.x; a0.y += p.x * val.y; a0.z += p.x * val.z; a0.w += p.x * val.w;
            a1.x += p.y * val.x; a1.y += p.y * val.y; a1.z += p.y * val.z; a1.w += p.y * val.w;
            a2.x += p.z * val.x; a2.y += p.z * val.y; a2.z += p.z * val.z; a2.w += p.z * val.w;
            a3.x += p.w * val.x; a3.y += p.w * val.y; a3.z += p.w * val.z; a3.w += p.w * val.w;
        }
    }

    // ---- stage 3: normalize + store (wave stores 4 consecutive t rows) ----
    const float4 nrm = *(const float4*)&s_norm[wid << 2];
    const int tt0 = t0 + (wid << 2);
    float* obase = out + ((size_t)b * T + tt0) * D + (lane << 2);
    { float4 o = {a0.x*nrm.x, a0.y*nrm.x, a0.z*nrm.x, a0.w*nrm.x}; *(float4*)(obase + 0*(size_t)D) = o; }
    { float4 o = {a1.x*nrm.y, a1.y*nrm.y, a1.z*nrm.y, a1.w*nrm.y}; *(float4*)(obase + 1*(size_t)D) = o; }
    { float4 o = {a2.x*nrm.z, a2.y*nrm.z, a2.z*nrm.z, a2.w*nrm.z}; *(float4*)(obase + 2*(size_t)D) = o; }
    { float4 o = {a3.x*nrm.w, a3.y*nrm.w, a3.z*nrm.w, a3.w*nrm.w}; *(float4*)(obase + 3*(size_t)D) = o; }
}

extern "C" void kernel_launch(void* const* d_in, const int* in_sizes, int n_in,
                              void* d_out, int out_size, void* d_ws, size_t ws_size,
                              hipStream_t stream) {
    const float* text = (const float*)d_in[0];
    const int*   durs = (const int*)d_in[1];
    float*       out  = (float*)d_out;

    const int BL = in_sizes[1];        // B * L
    const int D  = in_sizes[0] / BL;   // 256
    const int B  = BL / L;             // 16
    const int T  = out_size / (B * D); // 2048
    const int tilesPerB = (T + TILE_T - 1) / TILE_T;
    const int nwg = B * tilesPerB;     // 2048, divisible by 8

    ge_kernel<<<dim3(nwg), dim3(NTHREADS), 0, stream>>>(
        text, durs, out, B, D, T, tilesPerB, nwg);
}